// Round 5
// baseline (258.666 us; speedup 1.0000x reference)
//
#include <hip/hip_runtime.h>

#define NBINS   2048
#define NSLICE  16      // B*C = 4*4
#define BPS     128     // blocks per slice -> 2048 blocks total
#define BLOCK   256
#define NB      16      // float4 batches per thread per array

typedef float f32x4 __attribute__((ext_vector_type(4)));

static constexpr float kRange = 9.2104f;   // ce < -ln(1e-4) = 9.21034

// ws layout (bytes):
//  [0,64)    tmax u32[16]; [64,128) pmax u32[16]; [128,192) losses f32[16]
//  [256,...) histogram area:
//     store mode : partials u32[NSLICE*BPS*NBINS] = 16 MiB
//     atomic mode: hist     u32[NSLICE*NBINS]     = 128 KiB
#define WS_TMAX 0
#define WS_PMAX 64
#define WS_LOSS 128
#define WS_HIST 256
#define STORE_NEED (256 + (size_t)NSLICE * BPS * NBINS * 4)

__device__ __forceinline__ f32x4 ldg4(const float* base, unsigned voff) {
    f32x4 d;
    asm volatile("global_load_dwordx4 %0, %1, %2"
                 : "=v"(d) : "v"(voff), "s"(base));
    return d;
}
#define VMWAIT(N) do { asm volatile("s_waitcnt vmcnt(" #N ")"); \
                       __builtin_amdgcn_sched_barrier(0); } while (0)

__global__ __launch_bounds__(BLOCK, 4) void k_hist(
    const float* __restrict__ net, const float* __restrict__ tgt,
    const float* __restrict__ mp, unsigned* __restrict__ hist,
    unsigned* __restrict__ tmax, unsigned* __restrict__ pmax, int store_mode)
{
    __shared__ unsigned lcnt[NBINS];
    const int tid = threadIdx.x;
    for (int i = tid; i < NBINS; i += BLOCK) lcnt[i] = 0u;
    __syncthreads();

    const int slice = blockIdx.y;
    const float scale = (float)NBINS / kRange;
    // per-slice bytes = 524288 float4 * 16B = 8 MiB; block tile = 64 KiB
    const unsigned voff0 = (unsigned)slice * 8388608u +
                           (unsigned)blockIdx.x * 65536u + (unsigned)tid * 16u;

    f32x4 T[4], P[4], M[4];
    float ltm = 0.f, lpm = 0.f;

#define ISSUE3(s, b) do { unsigned vo = voff0 + (b) * 4096u;               \
        T[s] = ldg4(tgt, vo); P[s] = ldg4(net, vo); M[s] = ldg4(mp, vo);   \
    } while (0)

#define COMP(s) do {                                                       \
        _Pragma("unroll") for (int e = 0; e < 4; ++e) {                    \
            float tv = T[s][e], pv = P[s][e], mv = M[s][e];                \
            float ce = -tv * __logf(pv);                                   \
            int bin = (int)(ce * scale);                                   \
            bin = bin < 0 ? 0 : (bin > NBINS - 1 ? NBINS - 1 : bin);       \
            atomicAdd(&lcnt[bin], 1u);                                     \
            ltm = fmaxf(ltm, tv); lpm = fmaxf(lpm, mv);                    \
        } } while (0)

    // 12 loads always in flight; vmcnt(9) retires exactly one 3-load batch.
    ISSUE3(0, 0); ISSUE3(1, 1); ISSUE3(2, 2); ISSUE3(3, 3);
    VMWAIT(9); COMP(0); ISSUE3(0, 4);
    VMWAIT(9); COMP(1); ISSUE3(1, 5);
    VMWAIT(9); COMP(2); ISSUE3(2, 6);
    VMWAIT(9); COMP(3); ISSUE3(3, 7);
    VMWAIT(9); COMP(0); ISSUE3(0, 8);
    VMWAIT(9); COMP(1); ISSUE3(1, 9);
    VMWAIT(9); COMP(2); ISSUE3(2, 10);
    VMWAIT(9); COMP(3); ISSUE3(3, 11);
    VMWAIT(9); COMP(0); ISSUE3(0, 12);
    VMWAIT(9); COMP(1); ISSUE3(1, 13);
    VMWAIT(9); COMP(2); ISSUE3(2, 14);
    VMWAIT(9); COMP(3); ISSUE3(3, 15);
    VMWAIT(9); COMP(0);
    VMWAIT(6); COMP(1);
    VMWAIT(3); COMP(2);
    VMWAIT(0); COMP(3);

    __syncthreads();

    if (store_mode) {
        unsigned* dst = hist + ((size_t)slice * BPS + blockIdx.x) * NBINS;
        for (int i = tid; i < NBINS; i += BLOCK) dst[i] = lcnt[i];
    } else {
        for (int i = tid; i < NBINS; i += BLOCK) {
            unsigned c = lcnt[i];
            if (c) atomicAdd(&hist[slice * NBINS + i], c);
        }
    }

    // wave-reduce maxes (non-negative floats -> uint order-preserving)
    for (int off = 32; off; off >>= 1) {
        ltm = fmaxf(ltm, __shfl_down(ltm, off, 64));
        lpm = fmaxf(lpm, __shfl_down(lpm, off, 64));
    }
    if ((tid & 63) == 0) {
        atomicMax(&tmax[slice], __float_as_uint(ltm));
        atomicMax(&pmax[slice], __float_as_uint(lpm));
    }
}

// 16 blocks, one per slice: sum partials, find threshold bin, top-k mean.
__global__ __launch_bounds__(BLOCK) void k_select(
    const unsigned* __restrict__ hist, const unsigned* __restrict__ tmax,
    const unsigned* __restrict__ pmax, float* __restrict__ losses,
    unsigned k, int nparts)
{
    const int slice = blockIdx.x;
    const int tid = threadIdx.x;
    const unsigned* base = hist + (size_t)slice * nparts * NBINS;

    __shared__ unsigned scnt[BLOCK];
    __shared__ float    ssum[BLOCK];
    __shared__ int      sbin;
    __shared__ unsigned skrem;

    const float binw = kRange / (float)NBINS;
    const int BPT = NBINS / BLOCK;   // 8 bins per thread, descending order

    unsigned cj[BPT];
    unsigned mycnt = 0;
#pragma unroll
    for (int j = 0; j < BPT; ++j) {
        int bin = NBINS - 1 - (tid * BPT + j);
        unsigned c = 0;
        for (int p = 0; p < nparts; ++p) c += base[(size_t)p * NBINS + bin];
        cj[j] = c;
        mycnt += c;
    }
    scnt[tid] = mycnt;
    __syncthreads();

    unsigned P = 0;                        // exclusive prefix (naive, tiny)
    for (int u = 0; u < tid; ++u) P += scnt[u];

    if (P < k && P + mycnt >= k) {         // unique owner of the threshold bin
        unsigned cum = P;
#pragma unroll
        for (int j = 0; j < BPT; ++j) {
            unsigned c = cj[j];
            if (cum + c >= k) {
                sbin = NBINS - 1 - (tid * BPT + j);
                skrem = k - cum;
                break;
            }
            cum += c;
        }
    }
    __syncthreads();

    const int bstar = sbin;
    float mysum = 0.f;
#pragma unroll
    for (int j = 0; j < BPT; ++j) {
        int bin = NBINS - 1 - (tid * BPT + j);
        if (bin > bstar)
            mysum += (float)cj[j] * (((float)bin + 0.5f) * binw);
    }
    ssum[tid] = mysum;
    __syncthreads();
    for (int off = BLOCK / 2; off; off >>= 1) {
        if (tid < off) ssum[tid] += ssum[tid + off];
        __syncthreads();
    }

    if (tid == 0) {
        float total = ssum[0] + (float)skrem * (((float)bstar + 0.5f) * binw);
        float loss = total / (float)k;
        bool active = !((tmax[slice] == 0u) && (pmax[slice] == 0u));
        losses[slice] = active ? loss : 0.0f;
    }
}

__global__ void k_final(const float* __restrict__ losses, float* __restrict__ out)
{
    if (threadIdx.x == 0 && blockIdx.x == 0) {
        float total = 0.f;
        for (int b = 0; b < 4; ++b) {
            float s = 0.f;
            int cnt = 0;
            for (int c = 0; c < 4; ++c) {
                float l = losses[b * 4 + c];
                s += l;
                cnt += (l != 0.0f) ? 1 : 0;
            }
            total += s / (float)cnt;   // cnt==0 -> inf/nan, same as reference
        }
        out[0] = total / 4.0f;
    }
}

extern "C" void kernel_launch(void* const* d_in, const int* in_sizes, int n_in,
                              void* d_out, int out_size, void* d_ws, size_t ws_size,
                              hipStream_t stream) {
    const float* net = (const float*)d_in[0];
    const float* tgt = (const float*)d_in[1];
    const float* mp  = (const float*)d_in[2];
    float* out = (float*)d_out;

    const long long total = in_sizes[0];          // 33,554,432
    const long long V = total / NSLICE;           // 2,097,152
    const unsigned k = (unsigned)(V * 10 / 100);  // int(V*10/100) = 209,715

    char* ws = (char*)d_ws;
    unsigned* tmax   = (unsigned*)(ws + WS_TMAX);
    unsigned* pmax   = (unsigned*)(ws + WS_PMAX);
    float*    losses = (float*)(ws + WS_LOSS);
    unsigned* hist   = (unsigned*)(ws + WS_HIST);

    const int store_mode = (ws_size >= STORE_NEED) ? 1 : 0;
    const int nparts = store_mode ? BPS : 1;

    // store mode: partials fully overwritten every call -> only zero the tail
    hipMemsetAsync(d_ws, 0,
                   store_mode ? 256 : (256 + (size_t)NSLICE * NBINS * 4),
                   stream);

    dim3 grid1(BPS, NSLICE);
    k_hist<<<grid1, BLOCK, 0, stream>>>(net, tgt, mp, hist, tmax, pmax,
                                        store_mode);
    k_select<<<NSLICE, BLOCK, 0, stream>>>(hist, tmax, pmax, losses, k, nparts);
    k_final<<<1, 64, 0, stream>>>(losses, out);
}

// Round 6
// 226.350 us; speedup vs baseline: 1.1428x; 1.1428x over previous
//
#include <hip/hip_runtime.h>

#define NBINS   2048
#define NSLICE  16      // B*C = 4*4
#define BPS     128     // blocks per slice -> 2048 blocks total
#define BLOCK   256

typedef float f32x4 __attribute__((ext_vector_type(4)));

static constexpr float kRange = 9.2104f;   // ce < -ln(1e-4) = 9.21034

// ws layout (bytes):
//  [0,64) tmax u32[16]; [64,128) pmax u32[16]; [128,192) losses f32[16]
//  [256, 256+131072) hist u32[NSLICE*NBINS]
#define WS_TMAX 0
#define WS_PMAX 64
#define WS_LOSS 128
#define WS_HIST 256
#define WS_USED (256 + NSLICE * NBINS * 4)

__device__ __forceinline__ f32x4 ldg4(const float* base, unsigned voff) {
    f32x4 d;
    asm volatile("global_load_dwordx4 %0, %1, %2"
                 : "=v"(d) : "v"(voff), "s"(base));
    return d;
}
#define VMWAIT(N) do { asm volatile("s_waitcnt vmcnt(" #N ")"); \
                       __builtin_amdgcn_sched_barrier(0); } while (0)

// ---- histogram over net+tgt (2 streams), also tmax ----
__global__ __launch_bounds__(BLOCK, 4) void k_hist(
    const float* __restrict__ net, const float* __restrict__ tgt,
    unsigned* __restrict__ hist, unsigned* __restrict__ tmax)
{
    __shared__ unsigned lcnt[NBINS];
    const int tid = threadIdx.x;
    for (int i = tid; i < NBINS; i += BLOCK) lcnt[i] = 0u;
    __syncthreads();

    const int slice = blockIdx.y;
    const float scale = (float)NBINS / kRange;
    // per-slice bytes = 8 MiB; block tile = 64 KiB; batch stride = 4 KiB
    const unsigned voff0 = (unsigned)slice * 8388608u +
                           (unsigned)blockIdx.x * 65536u + (unsigned)tid * 16u;

    f32x4 T[4], P[4];
    float ltm = 0.f;

#define ISSUE2(s, b) do { unsigned vo = voff0 + (b) * 4096u;               \
        T[s] = ldg4(tgt, vo); P[s] = ldg4(net, vo); } while (0)

#define COMP(s) do {                                                       \
        _Pragma("unroll") for (int e = 0; e < 4; ++e) {                    \
            float tv = T[s][e], pv = P[s][e];                              \
            float ce = -tv * __logf(pv);                                   \
            int bin = (int)(ce * scale);                                   \
            bin = bin < 0 ? 0 : (bin > NBINS - 1 ? NBINS - 1 : bin);       \
            atomicAdd(&lcnt[bin], 1u);                                     \
            ltm = fmaxf(ltm, tv);                                          \
        } } while (0)

    // 8 loads in flight; vmcnt(6) retires exactly one 2-load batch.
    ISSUE2(0, 0); ISSUE2(1, 1); ISSUE2(2, 2); ISSUE2(3, 3);
    VMWAIT(6); COMP(0); ISSUE2(0, 4);
    VMWAIT(6); COMP(1); ISSUE2(1, 5);
    VMWAIT(6); COMP(2); ISSUE2(2, 6);
    VMWAIT(6); COMP(3); ISSUE2(3, 7);
    VMWAIT(6); COMP(0); ISSUE2(0, 8);
    VMWAIT(6); COMP(1); ISSUE2(1, 9);
    VMWAIT(6); COMP(2); ISSUE2(2, 10);
    VMWAIT(6); COMP(3); ISSUE2(3, 11);
    VMWAIT(6); COMP(0); ISSUE2(0, 12);
    VMWAIT(6); COMP(1); ISSUE2(1, 13);
    VMWAIT(6); COMP(2); ISSUE2(2, 14);
    VMWAIT(6); COMP(3); ISSUE2(3, 15);
    VMWAIT(6); COMP(0);
    VMWAIT(4); COMP(1);
    VMWAIT(2); COMP(2);
    VMWAIT(0); COMP(3);

    __syncthreads();

    for (int i = tid; i < NBINS; i += BLOCK) {
        unsigned c = lcnt[i];
        if (c) atomicAdd(&hist[slice * NBINS + i], c);
    }

    for (int off = 32; off; off >>= 1)
        ltm = fmaxf(ltm, __shfl_down(ltm, off, 64));
    if ((tid & 63) == 0) atomicMax(&tmax[slice], __float_as_uint(ltm));
}

// ---- pure streaming probe: pmax over mp (1 stream, no LDS/atomics in loop) --
__global__ __launch_bounds__(BLOCK, 4) void k_pmax(
    const float* __restrict__ mp, unsigned* __restrict__ pmax)
{
    const int tid = threadIdx.x;
    const int slice = blockIdx.y;
    const unsigned voff0 = (unsigned)slice * 8388608u +
                           (unsigned)blockIdx.x * 65536u + (unsigned)tid * 16u;

    f32x4 M[16];
#pragma unroll
    for (int b = 0; b < 16; ++b) M[b] = ldg4(mp, voff0 + b * 4096u);
    VMWAIT(0);

    float lpm = 0.f;
#pragma unroll
    for (int b = 0; b < 16; ++b) {
        lpm = fmaxf(lpm, fmaxf(fmaxf(M[b][0], M[b][1]),
                               fmaxf(M[b][2], M[b][3])));
    }
    for (int off = 32; off; off >>= 1)
        lpm = fmaxf(lpm, __shfl_down(lpm, off, 64));
    if ((tid & 63) == 0) atomicMax(&pmax[slice], __float_as_uint(lpm));
}

// 16 blocks, one per slice: find threshold bin, top-k mean (bin centers).
__global__ __launch_bounds__(BLOCK) void k_select(
    const unsigned* __restrict__ hist, const unsigned* __restrict__ tmax,
    const unsigned* __restrict__ pmax, float* __restrict__ losses, unsigned k)
{
    const int slice = blockIdx.x;
    const int tid = threadIdx.x;
    const unsigned* hc = hist + slice * NBINS;

    __shared__ unsigned scnt[BLOCK];
    __shared__ float    ssum[BLOCK];
    __shared__ int      sbin;
    __shared__ unsigned skrem;

    const float binw = kRange / (float)NBINS;
    const int BPT = NBINS / BLOCK;   // 8 bins per thread, descending order

    unsigned cj[BPT];
    unsigned mycnt = 0;
#pragma unroll
    for (int j = 0; j < BPT; ++j) {
        cj[j] = hc[NBINS - 1 - (tid * BPT + j)];
        mycnt += cj[j];
    }
    scnt[tid] = mycnt;
    __syncthreads();

    unsigned P = 0;                        // exclusive prefix (naive, tiny)
    for (int u = 0; u < tid; ++u) P += scnt[u];

    if (P < k && P + mycnt >= k) {         // unique owner of the threshold bin
        unsigned cum = P;
#pragma unroll
        for (int j = 0; j < BPT; ++j) {
            if (cum + cj[j] >= k) {
                sbin = NBINS - 1 - (tid * BPT + j);
                skrem = k - cum;
                break;
            }
            cum += cj[j];
        }
    }
    __syncthreads();

    const int bstar = sbin;
    float mysum = 0.f;
#pragma unroll
    for (int j = 0; j < BPT; ++j) {
        int bin = NBINS - 1 - (tid * BPT + j);
        if (bin > bstar)
            mysum += (float)cj[j] * (((float)bin + 0.5f) * binw);
    }
    ssum[tid] = mysum;
    __syncthreads();
    for (int off = BLOCK / 2; off; off >>= 1) {
        if (tid < off) ssum[tid] += ssum[tid + off];
        __syncthreads();
    }

    if (tid == 0) {
        float total = ssum[0] + (float)skrem * (((float)bstar + 0.5f) * binw);
        float loss = total / (float)k;
        bool active = !((tmax[slice] == 0u) && (pmax[slice] == 0u));
        losses[slice] = active ? loss : 0.0f;
    }
}

__global__ void k_final(const float* __restrict__ losses, float* __restrict__ out)
{
    if (threadIdx.x == 0 && blockIdx.x == 0) {
        float total = 0.f;
        for (int b = 0; b < 4; ++b) {
            float s = 0.f;
            int cnt = 0;
            for (int c = 0; c < 4; ++c) {
                float l = losses[b * 4 + c];
                s += l;
                cnt += (l != 0.0f) ? 1 : 0;
            }
            total += s / (float)cnt;   // cnt==0 -> inf/nan, same as reference
        }
        out[0] = total / 4.0f;
    }
}

extern "C" void kernel_launch(void* const* d_in, const int* in_sizes, int n_in,
                              void* d_out, int out_size, void* d_ws, size_t ws_size,
                              hipStream_t stream) {
    const float* net = (const float*)d_in[0];
    const float* tgt = (const float*)d_in[1];
    const float* mp  = (const float*)d_in[2];
    float* out = (float*)d_out;

    const long long total = in_sizes[0];          // 33,554,432
    const long long V = total / NSLICE;           // 2,097,152
    const unsigned k = (unsigned)(V * 10 / 100);  // int(V*10/100) = 209,715

    char* ws = (char*)d_ws;
    unsigned* tmax   = (unsigned*)(ws + WS_TMAX);
    unsigned* pmax   = (unsigned*)(ws + WS_PMAX);
    float*    losses = (float*)(ws + WS_LOSS);
    unsigned* hist   = (unsigned*)(ws + WS_HIST);

    hipMemsetAsync(d_ws, 0, WS_USED, stream);

    dim3 grid(BPS, NSLICE);
    k_pmax<<<grid, BLOCK, 0, stream>>>(mp, pmax);
    k_hist<<<grid, BLOCK, 0, stream>>>(net, tgt, hist, tmax);
    k_select<<<NSLICE, BLOCK, 0, stream>>>(hist, tmax, pmax, losses, k);
    k_final<<<1, 64, 0, stream>>>(losses, out);
}

// Round 7
// 219.311 us; speedup vs baseline: 1.1794x; 1.0321x over previous
//
#include <hip/hip_runtime.h>

#define NBINS   2048
#define NSLICE  16      // B*C = 4*4
#define BPS     256     // blocks per slice -> 4096 blocks total (k_hist)
#define BLOCK   256

typedef float f32x4 __attribute__((ext_vector_type(4)));

static constexpr float kRange = 9.2104f;   // ce < -ln(1e-4) = 9.21034

// ws layout (bytes):
//  [0,64) tmax u32[16]; [64,128) pmax u32[16]; [128,192) losses f32[16]
//  [256, 256+131072) hist u32[NSLICE*NBINS]
#define WS_TMAX 0
#define WS_PMAX 64
#define WS_LOSS 128
#define WS_HIST 256
#define WS_USED (256 + NSLICE * NBINS * 4)

__device__ __forceinline__ f32x4 ldg4(const float* base, unsigned voff) {
    f32x4 d;
    asm volatile("global_load_dwordx4 %0, %1, %2"
                 : "=v"(d) : "v"(voff), "s"(base));
    return d;
}
#define VMWAIT(N) do { asm volatile("s_waitcnt vmcnt(" #N ")"); \
                       __builtin_amdgcn_sched_barrier(0); } while (0)

// ---- histogram over net+tgt (2 streams, 16 loads in flight), also tmax ----
__global__ __launch_bounds__(BLOCK, 4) void k_hist(
    const float* __restrict__ net, const float* __restrict__ tgt,
    unsigned* __restrict__ hist, unsigned* __restrict__ tmax)
{
    __shared__ unsigned lcnt[NBINS];
    const int tid = threadIdx.x;
    for (int i = tid; i < NBINS; i += BLOCK) lcnt[i] = 0u;
    __syncthreads();

    const int slice = blockIdx.y;
    const float scale = (float)NBINS / kRange;
    // per-slice bytes = 8 MiB; block tile = 32 KiB; batch stride = 4 KiB
    const unsigned voff0 = (unsigned)slice * 8388608u +
                           (unsigned)blockIdx.x * 32768u + (unsigned)tid * 16u;

    f32x4 T[8], P[8];
    float ltm = 0.f;

#pragma unroll
    for (int b = 0; b < 8; ++b) {          // 16 loads issued, all in flight
        unsigned vo = voff0 + b * 4096u;
        T[b] = ldg4(tgt, vo);
        P[b] = ldg4(net, vo);
    }

#define COMP(s) do {                                                       \
        _Pragma("unroll") for (int e = 0; e < 4; ++e) {                    \
            float tv = T[s][e], pv = P[s][e];                              \
            float ce = -tv * __logf(pv);                                   \
            int bin = (int)(ce * scale);                                   \
            bin = bin < 0 ? 0 : (bin > NBINS - 1 ? NBINS - 1 : bin);       \
            atomicAdd(&lcnt[bin], 1u);                                     \
            ltm = fmaxf(ltm, tv);                                          \
        } } while (0)

    // loads retire in order: vmcnt(14) -> batch 0 done, etc.
    VMWAIT(14); COMP(0);
    VMWAIT(12); COMP(1);
    VMWAIT(10); COMP(2);
    VMWAIT(8);  COMP(3);
    VMWAIT(6);  COMP(4);
    VMWAIT(4);  COMP(5);
    VMWAIT(2);  COMP(6);
    VMWAIT(0);  COMP(7);

    __syncthreads();

    for (int i = tid; i < NBINS; i += BLOCK) {
        unsigned c = lcnt[i];
        if (c) atomicAdd(&hist[slice * NBINS + i], c);
    }

    for (int off = 32; off; off >>= 1)
        ltm = fmaxf(ltm, __shfl_down(ltm, off, 64));
    if ((tid & 63) == 0) atomicMax(&tmax[slice], __float_as_uint(ltm));
}

// ---- conditional pmax: only touches mp for slices whose tmax == 0 ----
// active = !(tmax==0 && pmax==0): when tmax != 0, pmax is irrelevant.
__global__ __launch_bounds__(BLOCK) void k_pmax_cond(
    const float* __restrict__ mp, const unsigned* __restrict__ tmax,
    unsigned* __restrict__ pmax)
{
    const int slice = blockIdx.y;
    if (tmax[slice] != 0u) return;         // uniform branch, block retires

    const int tid = threadIdx.x;
    const float4* m4 = (const float4*)mp + (size_t)slice * 524288 +
                       (size_t)blockIdx.x * 4096 + tid;
    float lpm = 0.f;
    for (int b = 0; b < 16; ++b) {
        float4 m = m4[b * BLOCK];
        lpm = fmaxf(lpm, fmaxf(fmaxf(m.x, m.y), fmaxf(m.z, m.w)));
    }
    for (int off = 32; off; off >>= 1)
        lpm = fmaxf(lpm, __shfl_down(lpm, off, 64));
    if ((tid & 63) == 0) atomicMax(&pmax[slice], __float_as_uint(lpm));
}

// 16 blocks, one per slice: find threshold bin, top-k mean (bin centers).
__global__ __launch_bounds__(BLOCK) void k_select(
    const unsigned* __restrict__ hist, const unsigned* __restrict__ tmax,
    const unsigned* __restrict__ pmax, float* __restrict__ losses, unsigned k)
{
    const int slice = blockIdx.x;
    const int tid = threadIdx.x;
    const unsigned* hc = hist + slice * NBINS;

    __shared__ unsigned scnt[BLOCK];
    __shared__ float    ssum[BLOCK];
    __shared__ int      sbin;
    __shared__ unsigned skrem;

    const float binw = kRange / (float)NBINS;
    const int BPT = NBINS / BLOCK;   // 8 bins per thread, descending order

    unsigned cj[BPT];
    unsigned mycnt = 0;
#pragma unroll
    for (int j = 0; j < BPT; ++j) {
        cj[j] = hc[NBINS - 1 - (tid * BPT + j)];
        mycnt += cj[j];
    }
    scnt[tid] = mycnt;
    __syncthreads();

    unsigned P = 0;                        // exclusive prefix (naive, tiny)
    for (int u = 0; u < tid; ++u) P += scnt[u];

    if (P < k && P + mycnt >= k) {         // unique owner of the threshold bin
        unsigned cum = P;
#pragma unroll
        for (int j = 0; j < BPT; ++j) {
            if (cum + cj[j] >= k) {
                sbin = NBINS - 1 - (tid * BPT + j);
                skrem = k - cum;
                break;
            }
            cum += cj[j];
        }
    }
    __syncthreads();

    const int bstar = sbin;
    float mysum = 0.f;
#pragma unroll
    for (int j = 0; j < BPT; ++j) {
        int bin = NBINS - 1 - (tid * BPT + j);
        if (bin > bstar)
            mysum += (float)cj[j] * (((float)bin + 0.5f) * binw);
    }
    ssum[tid] = mysum;
    __syncthreads();
    for (int off = BLOCK / 2; off; off >>= 1) {
        if (tid < off) ssum[tid] += ssum[tid + off];
        __syncthreads();
    }

    if (tid == 0) {
        float total = ssum[0] + (float)skrem * (((float)bstar + 0.5f) * binw);
        float loss = total / (float)k;
        bool active = !((tmax[slice] == 0u) && (pmax[slice] == 0u));
        losses[slice] = active ? loss : 0.0f;
    }
}

__global__ void k_final(const float* __restrict__ losses, float* __restrict__ out)
{
    if (threadIdx.x == 0 && blockIdx.x == 0) {
        float total = 0.f;
        for (int b = 0; b < 4; ++b) {
            float s = 0.f;
            int cnt = 0;
            for (int c = 0; c < 4; ++c) {
                float l = losses[b * 4 + c];
                s += l;
                cnt += (l != 0.0f) ? 1 : 0;
            }
            total += s / (float)cnt;   // cnt==0 -> inf/nan, same as reference
        }
        out[0] = total / 4.0f;
    }
}

extern "C" void kernel_launch(void* const* d_in, const int* in_sizes, int n_in,
                              void* d_out, int out_size, void* d_ws, size_t ws_size,
                              hipStream_t stream) {
    const float* net = (const float*)d_in[0];
    const float* tgt = (const float*)d_in[1];
    const float* mp  = (const float*)d_in[2];
    float* out = (float*)d_out;

    const long long total = in_sizes[0];          // 33,554,432
    const long long V = total / NSLICE;           // 2,097,152
    const unsigned k = (unsigned)(V * 10 / 100);  // int(V*10/100) = 209,715

    char* ws = (char*)d_ws;
    unsigned* tmax   = (unsigned*)(ws + WS_TMAX);
    unsigned* pmax   = (unsigned*)(ws + WS_PMAX);
    float*    losses = (float*)(ws + WS_LOSS);
    unsigned* hist   = (unsigned*)(ws + WS_HIST);

    hipMemsetAsync(d_ws, 0, WS_USED, stream);

    dim3 gridh(BPS, NSLICE);
    k_hist<<<gridh, BLOCK, 0, stream>>>(net, tgt, hist, tmax);
    dim3 gridp(128, NSLICE);
    k_pmax_cond<<<gridp, BLOCK, 0, stream>>>(mp, tmax, pmax);
    k_select<<<NSLICE, BLOCK, 0, stream>>>(hist, tmax, pmax, losses, k);
    k_final<<<1, 64, 0, stream>>>(losses, out);
}

// Round 9
// 129.528 us; speedup vs baseline: 1.9970x; 1.6932x over previous
//
#include <hip/hip_runtime.h>

#define NBINS   2048
#define NSLICE  16      // B*C = 4*4
#define BPS     64      // blocks per slice (k_hist) -> 1024 blocks total
#define BLOCK   256

typedef float f32x4 __attribute__((ext_vector_type(4)));

static constexpr float kRange = 9.2104f;   // ce < -ln(1e-4) = 9.21034

// ws layout (bytes):
//  [0,64) tmax u32[16]; [64,128) pmax u32[16]; [128,192) losses f32[16]
//  [256, 256+131072) hist u32[NSLICE*NBINS]
#define WS_TMAX 0
#define WS_PMAX 64
#define WS_LOSS 128
#define WS_HIST 256
#define WS_USED (256 + NSLICE * NBINS * 4)

__device__ __forceinline__ f32x4 ldg4(const float* base, unsigned voff) {
    f32x4 d;
    asm volatile("global_load_dwordx4 %0, %1, %2"
                 : "=v"(d) : "v"(voff), "s"(base));
    return d;
}
#define VMWAIT(N) do { asm volatile("s_waitcnt vmcnt(" #N ")"); \
                       __builtin_amdgcn_sched_barrier(0); } while (0)

// ---- histogram over net+tgt: 4 pseudo-streams (2 arrays x 2 half-tiles),
//      3-deep rotation = 12 loads in flight, also computes tmax ----
__global__ __launch_bounds__(BLOCK, 4) void k_hist(
    const float* __restrict__ net, const float* __restrict__ tgt,
    unsigned* __restrict__ hist, unsigned* __restrict__ tmax)
{
    __shared__ unsigned lcnt[NBINS];
    const int tid = threadIdx.x;
    for (int i = tid; i < NBINS; i += BLOCK) lcnt[i] = 0u;
    __syncthreads();

    const int slice = blockIdx.y;
    const float scale = (float)NBINS / kRange;
    // per-slice 8 MiB; block tile 128 KiB = two 64 KiB half-tiles
    const unsigned voff0 = (unsigned)slice * 8388608u +
                           (unsigned)blockIdx.x * 131072u + (unsigned)tid * 16u;

    // rotation register groups A/B/C: each {T_0, P_0, T_1, P_1}
    f32x4 TA0, PA0, TA1, PA1, TB0, PB0, TB1, PB1, TC0, PC0, TC1, PC1;
    float ltm = 0.f;

#define ISS(G, g) do { unsigned vo = voff0 + (g) * 4096u;                   \
        T##G##0 = ldg4(tgt, vo);          P##G##0 = ldg4(net, vo);          \
        T##G##1 = ldg4(tgt, vo + 65536u); P##G##1 = ldg4(net, vo + 65536u); \
    } while (0)

#define CPAIR(Tv, Pv) do {                                                  \
        _Pragma("unroll") for (int e = 0; e < 4; ++e) {                     \
            float tv = Tv[e], pv = Pv[e];                                   \
            float ce = -tv * __logf(pv);                                    \
            int bin = (int)(ce * scale);                                    \
            bin = bin < 0 ? 0 : (bin > NBINS - 1 ? NBINS - 1 : bin);        \
            atomicAdd(&lcnt[bin], 1u);                                      \
            ltm = fmaxf(ltm, tv);                                           \
        } } while (0)

#define CMP(G) do { CPAIR(T##G##0, P##G##0); CPAIR(T##G##1, P##G##1); } while (0)

    ISS(A, 0); ISS(B, 1); ISS(C, 2);
    VMWAIT(8); CMP(A); ISS(A, 3);
    VMWAIT(8); CMP(B); ISS(B, 4);
    VMWAIT(8); CMP(C); ISS(C, 5);
    VMWAIT(8); CMP(A); ISS(A, 6);
    VMWAIT(8); CMP(B); ISS(B, 7);
    VMWAIT(8); CMP(C); ISS(C, 8);
    VMWAIT(8); CMP(A); ISS(A, 9);
    VMWAIT(8); CMP(B); ISS(B, 10);
    VMWAIT(8); CMP(C); ISS(C, 11);
    VMWAIT(8); CMP(A); ISS(A, 12);
    VMWAIT(8); CMP(B); ISS(B, 13);
    VMWAIT(8); CMP(C); ISS(C, 14);
    VMWAIT(8); CMP(A); ISS(A, 15);
    VMWAIT(8); CMP(B);
    VMWAIT(4); CMP(C);
    VMWAIT(0); CMP(A);

    __syncthreads();

    for (int i = tid; i < NBINS; i += BLOCK) {
        unsigned c = lcnt[i];
        if (c) atomicAdd(&hist[slice * NBINS + i], c);
    }

    for (int off = 32; off; off >>= 1)
        ltm = fmaxf(ltm, __shfl_down(ltm, off, 64));
    if ((tid & 63) == 0) atomicMax(&tmax[slice], __float_as_uint(ltm));
}

// ---- m13-shape probe doing real work: pmax over mp.
// Plain HIP float4, 1D grid, grid-stride, no asm, no launch_bounds.
__global__ void k_pmax_m13(const float* __restrict__ mp,
                           unsigned* __restrict__ pmax, int nvec4)
{
    __shared__ unsigned spmax[NSLICE];
    const int tid = threadIdx.x;
    if (tid < NSLICE) spmax[tid] = 0u;
    __syncthreads();

    const float4* m4 = (const float4*)mp;
    const int stride = gridDim.x * BLOCK;
    for (int i = blockIdx.x * BLOCK + tid; i < nvec4; i += stride) {
        float4 m = m4[i];
        float lpm = fmaxf(fmaxf(m.x, m.y), fmaxf(m.z, m.w));
        for (int off = 32; off; off >>= 1)
            lpm = fmaxf(lpm, __shfl_down(lpm, off, 64));
        if ((tid & 63) == 0)                 // slice = i>>19, wave-uniform
            atomicMax(&spmax[i >> 19], __float_as_uint(lpm));
    }
    __syncthreads();
    if (tid < NSLICE) {
        unsigned v = spmax[tid];
        if (v) atomicMax(&pmax[tid], v);
    }
}

// 16 blocks, one per slice: find threshold bin, top-k mean (bin centers).
__global__ __launch_bounds__(BLOCK) void k_select(
    const unsigned* __restrict__ hist, const unsigned* __restrict__ tmax,
    const unsigned* __restrict__ pmax, float* __restrict__ losses, unsigned k)
{
    const int slice = blockIdx.x;
    const int tid = threadIdx.x;
    const unsigned* hc = hist + slice * NBINS;

    __shared__ unsigned scnt[BLOCK];
    __shared__ float    ssum[BLOCK];
    __shared__ int      sbin;
    __shared__ unsigned skrem;

    const float binw = kRange / (float)NBINS;
    const int BPT = NBINS / BLOCK;   // 8 bins per thread, descending order

    unsigned cj[BPT];
    unsigned mycnt = 0;
#pragma unroll
    for (int j = 0; j < BPT; ++j) {
        cj[j] = hc[NBINS - 1 - (tid * BPT + j)];
        mycnt += cj[j];
    }
    scnt[tid] = mycnt;
    __syncthreads();

    unsigned P = 0;                        // exclusive prefix (naive, tiny)
    for (int u = 0; u < tid; ++u) P += scnt[u];

    if (P < k && P + mycnt >= k) {         // unique owner of the threshold bin
        unsigned cum = P;
#pragma unroll
        for (int j = 0; j < BPT; ++j) {
            if (cum + cj[j] >= k) {
                sbin = NBINS - 1 - (tid * BPT + j);
                skrem = k - cum;
                break;
            }
            cum += cj[j];
        }
    }
    __syncthreads();

    const int bstar = sbin;
    float mysum = 0.f;
#pragma unroll
    for (int j = 0; j < BPT; ++j) {
        int bin = NBINS - 1 - (tid * BPT + j);
        if (bin > bstar)
            mysum += (float)cj[j] * (((float)bin + 0.5f) * binw);
    }
    ssum[tid] = mysum;
    __syncthreads();
    for (int off = BLOCK / 2; off; off >>= 1) {
        if (tid < off) ssum[tid] += ssum[tid + off];
        __syncthreads();
    }

    if (tid == 0) {
        float total = ssum[0] + (float)skrem * (((float)bstar + 0.5f) * binw);
        float loss = total / (float)k;
        bool active = !((tmax[slice] == 0u) && (pmax[slice] == 0u));
        losses[slice] = active ? loss : 0.0f;
    }
}

__global__ void k_final(const float* __restrict__ losses, float* __restrict__ out)
{
    if (threadIdx.x == 0 && blockIdx.x == 0) {
        float total = 0.f;
        for (int b = 0; b < 4; ++b) {
            float s = 0.f;
            int cnt = 0;
            for (int c = 0; c < 4; ++c) {
                float l = losses[b * 4 + c];
                s += l;
                cnt += (l != 0.0f) ? 1 : 0;
            }
            total += s / (float)cnt;   // cnt==0 -> inf/nan, same as reference
        }
        out[0] = total / 4.0f;
    }
}

extern "C" void kernel_launch(void* const* d_in, const int* in_sizes, int n_in,
                              void* d_out, int out_size, void* d_ws, size_t ws_size,
                              hipStream_t stream) {
    const float* net = (const float*)d_in[0];
    const float* tgt = (const float*)d_in[1];
    const float* mp  = (const float*)d_in[2];
    float* out = (float*)d_out;

    const long long total = in_sizes[0];          // 33,554,432
    const long long V = total / NSLICE;           // 2,097,152
    const unsigned k = (unsigned)(V * 10 / 100);  // int(V*10/100) = 209,715
    const int nvec4 = (int)(total / 4);           // 8,388,608

    char* ws = (char*)d_ws;
    unsigned* tmax   = (unsigned*)(ws + WS_TMAX);
    unsigned* pmax   = (unsigned*)(ws + WS_PMAX);
    float*    losses = (float*)(ws + WS_LOSS);
    unsigned* hist   = (unsigned*)(ws + WS_HIST);

    hipMemsetAsync(d_ws, 0, WS_USED, stream);

    dim3 gridh(BPS, NSLICE);
    k_hist<<<gridh, BLOCK, 0, stream>>>(net, tgt, hist, tmax);
    k_pmax_m13<<<2048, BLOCK, 0, stream>>>(mp, pmax, nvec4);
    k_select<<<NSLICE, BLOCK, 0, stream>>>(hist, tmax, pmax, losses, k);
    k_final<<<1, 64, 0, stream>>>(losses, out);
}